// Round 13
// baseline (1073.285 us; speedup 1.0000x reference)
//
#include <hip/hip_runtime.h>
#include <hip/hip_bf16.h>

// ---------------------------------------------------------------------------
// MolecularGNN: atom proj -> 6x (GATConv + BN + ReLU) -> mean pool -> MLP
// Round 13: non-temporal stores on all streamed outputs (xb/hb/xn/as/ad/C).
// R12 counters: agg FETCH 105MB vs ~56MB read-set -> ~50MB = xb size =>
// write-allocate/RFO on output stores. nt stores skip the allocate; outputs
// are consumed from HBM by the next kernel anyway (hb provably not L3-hot).
// ---------------------------------------------------------------------------

#define N_NODES 50000
#define N_EDGES 150000
#define N_GRAPHS 2000
#define ATOM_DIM 100
#define HID 512
#define HEADS 8
#define HEAD_DIM 64
#define LAYERS 6
#define TARGETS 13
#define NBINS 128
#define BK 64

typedef __attribute__((ext_vector_type(8))) short bf16x8;
typedef __attribute__((ext_vector_type(4))) float f32x4;

__device__ __forceinline__ float lrelu(float v) { return v > 0.f ? v : 0.2f * v; }

__device__ __forceinline__ unsigned short f2bf(float v) {
    __hip_bfloat16 b = __float2bfloat16(v);
    return *reinterpret_cast<unsigned short*>(&b);
}
__device__ __forceinline__ float bf2f(unsigned short u) {
    unsigned int x = ((unsigned int)u) << 16;
    return __uint_as_float(x);
}

typedef __attribute__((address_space(3))) unsigned int lds_uint;
typedef __attribute__((address_space(1))) const unsigned int glob_uint;

__device__ __forceinline__ void gload_lds16(const void* g, void* l) {
    __builtin_amdgcn_global_load_lds((glob_uint*)g, (lds_uint*)l, 16, 0, 0);
}

// ---------------- weight transpose + bf16 convert (layer weights) ----------
__global__ void wtrans_kernel(const float* __restrict__ W, __hip_bfloat16* __restrict__ Wt) {
    __shared__ float t[32][33];
    int l = blockIdx.z;
    int k0 = blockIdx.x * 32, m0 = blockIdx.y * 32;
    const float* Wl = W + (size_t)l * HID * HID;
    __hip_bfloat16* Wtl = Wt + (size_t)l * HID * HID;
#pragma unroll
    for (int i = 0; i < 32; i += 8)
        t[threadIdx.y + i][threadIdx.x] = Wl[(size_t)(k0 + threadIdx.y + i) * HID + m0 + threadIdx.x];
    __syncthreads();
#pragma unroll
    for (int i = 0; i < 32; i += 8)
        Wtl[(size_t)(m0 + threadIdx.y + i) * HID + k0 + threadIdx.x] =
            __float2bfloat16(t[threadIdx.x][threadIdx.y + i]);
}

// ---------------- atom_w transpose: Wt0[m][k] = bf16(atom_w[k][m]), k pad 128
__global__ void atomwt_kernel(const float* __restrict__ aw, __hip_bfloat16* __restrict__ Wt0) {
    int idx = blockIdx.x * 256 + threadIdx.x; // 512*128 total
    if (idx >= HID * 128) return;
    int k = idx >> 9, m = idx & (HID - 1);
    float v = (k < ATOM_DIM) ? aw[(size_t)k * HID + m] : 0.f;
    Wt0[(size_t)m * 128 + k] = __float2bfloat16(v);
}

// ---------------- atom projection MFMA: xn[N,512] = bf16(atom) @ Wt0^T + b -
__launch_bounds__(256)
__global__ void gemm_atom_kernel(const float* __restrict__ A,
                                 const __hip_bfloat16* __restrict__ Bt,
                                 const float* __restrict__ bias,
                                 __hip_bfloat16* __restrict__ Cb, int N) {
    constexpr int KP = 128;
    constexpr int LDA = 40;
    __shared__ __align__(16) short As[128 * LDA];
    __shared__ __align__(16) short Bs[128 * LDA];
    const int tid = threadIdx.x;
    const int wave = tid >> 6, lane = tid & 63;
    const int row0 = blockIdx.x * 128, col0 = blockIdx.y * 128;
    const int wr = (wave >> 1) * 64, wc = (wave & 1) * 64;
    const int q = lane >> 4, r16 = lane & 15;
    f32x4 acc[4][4] = {};

    for (int k0 = 0; k0 < KP; k0 += 32) {
#pragma unroll
        for (int c = tid; c < 512; c += 256) {
            int rrow = c >> 2, koff = (c & 3) << 3;
            int grow = row0 + rrow;
            int kb = k0 + koff;
            float vv[8];
            if (grow < N && kb + 8 <= ATOM_DIM) {
                const float* ap = A + (size_t)grow * ATOM_DIM + kb;
                float4 v0 = *reinterpret_cast<const float4*>(ap);
                float4 v1 = *reinterpret_cast<const float4*>(ap + 4);
                vv[0] = v0.x; vv[1] = v0.y; vv[2] = v0.z; vv[3] = v0.w;
                vv[4] = v1.x; vv[5] = v1.y; vv[6] = v1.z; vv[7] = v1.w;
            } else {
#pragma unroll
                for (int t = 0; t < 8; ++t)
                    vv[t] = (grow < N && kb + t < ATOM_DIM) ? A[(size_t)grow * ATOM_DIM + kb + t] : 0.f;
            }
            ushort4 p0, p1;
            p0.x = f2bf(vv[0]); p0.y = f2bf(vv[1]); p0.z = f2bf(vv[2]); p0.w = f2bf(vv[3]);
            p1.x = f2bf(vv[4]); p1.y = f2bf(vv[5]); p1.z = f2bf(vv[6]); p1.w = f2bf(vv[7]);
            *reinterpret_cast<ushort4*>(&As[rrow * LDA + koff]) = p0;
            *reinterpret_cast<ushort4*>(&As[rrow * LDA + koff + 4]) = p1;
            float4 w = *reinterpret_cast<const float4*>(Bt + (size_t)(col0 + rrow) * KP + kb);
            *reinterpret_cast<float4*>(&Bs[rrow * LDA + koff]) = w;
        }
        __syncthreads();
        bf16x8 a[4], b[4];
#pragma unroll
        for (int i = 0; i < 4; ++i)
            a[i] = *reinterpret_cast<const bf16x8*>(&As[(wr + i * 16 + r16) * LDA + q * 8]);
#pragma unroll
        for (int j = 0; j < 4; ++j)
            b[j] = *reinterpret_cast<const bf16x8*>(&Bs[(wc + j * 16 + r16) * LDA + q * 8]);
#pragma unroll
        for (int i = 0; i < 4; ++i)
#pragma unroll
            for (int j = 0; j < 4; ++j)
                acc[i][j] = __builtin_amdgcn_mfma_f32_16x16x32_bf16(a[i], b[j], acc[i][j], 0, 0, 0);
        __syncthreads();
    }

#pragma unroll
    for (int i = 0; i < 4; ++i) {
#pragma unroll
        for (int rr = 0; rr < 4; ++rr) {
            int grow = row0 + wr + i * 16 + q * 4 + rr;
            if (grow >= N) continue;
#pragma unroll
            for (int j = 0; j < 4; ++j) {
                int col = col0 + wc + j * 16 + r16;
                __builtin_nontemporal_store(
                    (short)f2bf(acc[i][j][rr] + bias[col]),
                    (short*)(Cb + (size_t)grow * HID + col));
            }
        }
    }
}

// ---------------- bf16 MFMA GEMM (m97 structure) + alpha epilogue ----------
// 128x256 tile, 512 threads = 8 waves, BK=64, XOR-swizzled LDS.
// HAS_BN=0: A via global_load_lds. HAS_BN=1: A via VGPR ds_write with fused
// fp32 relu(x*sc+sh). B always global_load_lds. All outputs nt-stored.
template <int HAS_BN>
__launch_bounds__(512)
__global__ void gemm_mfma_kernel(const __hip_bfloat16* __restrict__ A,
                                 const __hip_bfloat16* __restrict__ Bt,
                                 __hip_bfloat16* __restrict__ Cb,
                                 const float* __restrict__ bn_sc,
                                 const float* __restrict__ bn_sh,
                                 const float* __restrict__ att_s,
                                 const float* __restrict__ att_d,
                                 float* __restrict__ as_out,
                                 float* __restrict__ ad_out,
                                 int N) {
    constexpr int K = HID;
    __shared__ __align__(16) short As[128 * BK];   // 16 KB
    __shared__ __align__(16) short Bs[256 * BK];   // 32 KB
    __shared__ float scs[HID], shs[HID];
    const int tid = threadIdx.x;
    const int wave = tid >> 6, lane = tid & 63;
    const int row0 = blockIdx.x * 128, col0 = blockIdx.y * 256;
    const int wr = (wave >> 2) * 64, wc = (wave & 3) * 64;
    const int q = lane >> 4, r16 = lane & 15;
    f32x4 acc[4][4] = {};

    if (HAS_BN) {
        if (tid < HID) { scs[tid] = bn_sc[tid]; shs[tid] = bn_sh[tid]; }
        __syncthreads();
    }

    int arows[2], agchs[2];
#pragma unroll
    for (int is = 0; is < 2; ++is) {
        int fc = (wave * 2 + is) * 64 + lane;
        int row = fc >> 3;
        arows[is] = row;
        agchs[is] = (fc & 7) ^ (row & 7);
    }
    int brows[4], bgchs[4];
#pragma unroll
    for (int is = 0; is < 4; ++is) {
        int fc = (wave * 4 + is) * 64 + lane;
        int row = fc >> 3;
        brows[is] = row;
        bgchs[is] = (fc & 7) ^ (row & 7);
    }

    for (int k0 = 0; k0 < K; k0 += BK) {
        if (!HAS_BN) {
#pragma unroll
            for (int is = 0; is < 2; ++is) {
                int gra = row0 + arows[is]; if (gra > N - 1) gra = N - 1;
                gload_lds16(A + (size_t)gra * K + k0 + agchs[is] * 8, &As[(wave * 2 + is) * 512]);
            }
        } else {
#pragma unroll
            for (int is = 0; is < 2; ++is) {
                int gra = row0 + arows[is]; if (gra > N - 1) gra = N - 1;
                int cc = k0 + agchs[is] * 8;
                bf16x8 v = *reinterpret_cast<const bf16x8*>(A + (size_t)gra * K + cc);
                bf16x8 o;
#pragma unroll
                for (int t = 0; t < 8; ++t) {
                    float val = fmaf(bf2f((unsigned short)v[t]), scs[cc + t], shs[cc + t]);
                    o[t] = (short)f2bf(val > 0.f ? val : 0.f);
                }
                *reinterpret_cast<bf16x8*>(&As[((wave * 2 + is) * 64 + lane) * 8]) = o;
            }
        }
#pragma unroll
        for (int is = 0; is < 4; ++is) {
            gload_lds16(Bt + (size_t)(col0 + brows[is]) * K + k0 + bgchs[is] * 8,
                        &Bs[(wave * 4 + is) * 512]);
        }
        __syncthreads();
#pragma unroll
        for (int kk = 0; kk < 2; ++kk) {
            bf16x8 a[4], b[4];
#pragma unroll
            for (int i = 0; i < 4; ++i) {
                int row = wr + i * 16 + r16;
                int sw = (kk * 4 + q) ^ (row & 7);
                a[i] = *reinterpret_cast<const bf16x8*>(&As[row * BK + sw * 8]);
            }
#pragma unroll
            for (int j = 0; j < 4; ++j) {
                int row = wc + j * 16 + r16;
                int sw = (kk * 4 + q) ^ (row & 7);
                b[j] = *reinterpret_cast<const bf16x8*>(&Bs[row * BK + sw * 8]);
            }
#pragma unroll
            for (int i = 0; i < 4; ++i)
#pragma unroll
                for (int j = 0; j < 4; ++j)
                    acc[i][j] = __builtin_amdgcn_mfma_f32_16x16x32_bf16(a[i], b[j], acc[i][j], 0, 0, 0);
        }
        __syncthreads();
    }

    // C write (bf16, nt). C/D layout: col = lane&15, row = (lane>>4)*4 + reg
#pragma unroll
    for (int i = 0; i < 4; ++i) {
#pragma unroll
        for (int rr = 0; rr < 4; ++rr) {
            int grow = row0 + wr + i * 16 + q * 4 + rr;
            if (grow >= N) continue;
#pragma unroll
            for (int j = 0; j < 4; ++j)
                __builtin_nontemporal_store(
                    (short)f2bf(acc[i][j][rr]),
                    (short*)(Cb + (size_t)grow * HID + col0 + wc + j * 16 + r16));
        }
    }

    // Fused alpha: wave's 64 cols == one head
    const int head = (col0 + wc) >> 6;
    float avs[4], avd[4];
#pragma unroll
    for (int j = 0; j < 4; ++j) {
        avs[j] = att_s[col0 + wc + j * 16 + r16];
        avd[j] = att_d[col0 + wc + j * 16 + r16];
    }
#pragma unroll
    for (int i = 0; i < 4; ++i) {
#pragma unroll
        for (int rr = 0; rr < 4; ++rr) {
            float ss = 0.f, dd = 0.f;
#pragma unroll
            for (int j = 0; j < 4; ++j) {
                float v = acc[i][j][rr];
                ss += v * avs[j];
                dd += v * avd[j];
            }
#pragma unroll
            for (int off = 8; off > 0; off >>= 1) {
                ss += __shfl_xor(ss, off);
                dd += __shfl_xor(dd, off);
            }
            int grow = row0 + wr + i * 16 + q * 4 + rr;
            if (r16 == 0 && grow < N) {
                __builtin_nontemporal_store(ss, as_out + (size_t)grow * HEADS + head);
                __builtin_nontemporal_store(dd, ad_out + (size_t)grow * HEADS + head);
            }
        }
    }
}

// ---------------- count: edge dst bins + graph bins in one pass ------------
__global__ void count_kernel(const int* __restrict__ ei, const int* __restrict__ batch,
                             int* __restrict__ counts, int* __restrict__ gc) {
    int e = blockIdx.x * blockDim.x + threadIdx.x;
    int tot = N_EDGES + N_NODES;
    if (e < tot) {
        int dst = e < N_EDGES ? ei[N_EDGES + e] : e - N_EDGES;
        atomicAdd(&counts[dst], 1);
    }
    if (e < N_NODES) atomicAdd(&gc[batch[e]], 1);
}

__global__ void scan1_kernel(const int* __restrict__ counts, int* __restrict__ offsets,
                             int* __restrict__ bsums, int n) {
    __shared__ int tmp[1024];
    int tid = threadIdx.x;
    int gid = blockIdx.x * 1024 + tid;
    tmp[tid] = gid < n ? counts[gid] : 0;
    __syncthreads();
    for (int off = 1; off < 1024; off <<= 1) {
        int t = tid >= off ? tmp[tid - off] : 0;
        __syncthreads();
        tmp[tid] += t;
        __syncthreads();
    }
    if (gid < n) offsets[gid + 1] = tmp[tid];
    if (tid == 1023) bsums[blockIdx.x] = tmp[1023];
}

__global__ void scan2_kernel(int* bsums, int nb) {
    if (threadIdx.x == 0) {
        int s = 0;
        for (int i = 0; i < nb; ++i) { s += bsums[i]; bsums[i] = s; }
    }
}

__global__ void scan3_kernel(const int* __restrict__ counts, int* __restrict__ offsets,
                             const int* __restrict__ bsums, int* __restrict__ wp, int n) {
    int tid = threadIdx.x;
    int gid = blockIdx.x * 1024 + tid;
    if (gid == 0) offsets[0] = 0;
    if (gid >= n) return;
    int add = blockIdx.x > 0 ? bsums[blockIdx.x - 1] : 0;
    int v = offsets[gid + 1] + add;
    offsets[gid + 1] = v;
    wp[gid] = v - counts[gid];
}

__global__ void scatter_kernel(const int* __restrict__ ei, int* __restrict__ wp,
                               int* __restrict__ csrc) {
    int e = blockIdx.x * blockDim.x + threadIdx.x;
    int tot = N_EDGES + N_NODES;
    if (e >= tot) return;
    int src = e < N_EDGES ? ei[e] : e - N_EDGES;
    int dst = e < N_EDGES ? ei[N_EDGES + e] : e - N_EDGES;
    int pos = atomicAdd(&wp[dst], 1);
    csrc[pos] = src;
}

// ---------------- softmax-attention aggregation + fused BN stats -----------
// 16 dst nodes / block (2 per wave). Lane owns 8 channels. nt row stores.
__launch_bounds__(512)
__global__ void agg_kernel(const __hip_bfloat16* __restrict__ hb, const float* __restrict__ as,
                           const float* __restrict__ ad, const int* __restrict__ offsets,
                           const int* __restrict__ csrc, const float* __restrict__ bias,
                           __hip_bfloat16* __restrict__ outb,
                           float* __restrict__ ps, float* __restrict__ pq) {
    __shared__ float psum[16][HID];
    const int wave = threadIdx.x >> 6, lane = threadIdx.x & 63;
    const int head = lane >> 3;
    const int c0 = lane << 3;
    const float4* bp = reinterpret_cast<const float4*>(bias + c0);
    float4 b0 = bp[0], b1 = bp[1];
    float bb[8] = {b0.x, b0.y, b0.z, b0.w, b1.x, b1.y, b1.z, b1.w};

#pragma unroll
    for (int sub = 0; sub < 2; ++sub) {
        const int i = blockIdx.x * 16 + wave * 2 + sub;
        const int beg = offsets[i];
        const int deg = offsets[i + 1] - beg;
        const float adv = ad[(size_t)i * HEADS + head];

        float a[8] = {};
        float den = 0.f;
        for (int e0 = 0; e0 < deg; e0 += 4) {
            int m = deg - e0; if (m > 4) m = 4;
            int s[4];
#pragma unroll
            for (int k = 0; k < 4; ++k) {
                int kk = k < m ? k : m - 1;
                s[k] = csrc[beg + e0 + kk];
            }
            float w[4];
#pragma unroll
            for (int k = 0; k < 4; ++k)
                w[k] = (k < m) ? __expf(lrelu(as[(size_t)s[k] * HEADS + head] + adv)) : 0.f;
#pragma unroll
            for (int k = 0; k < 4; ++k) {
                bf16x8 hv = *reinterpret_cast<const bf16x8*>(hb + (size_t)s[k] * HID + c0);
#pragma unroll
                for (int t = 0; t < 8; ++t)
                    a[t] += w[k] * bf2f((unsigned short)hv[t]);
                den += w[k];
            }
        }
        float inv = 1.f / den;
        float o[8];
        bf16x8 ov;
#pragma unroll
        for (int t = 0; t < 8; ++t) {
            o[t] = a[t] * inv + bb[t];
            ov[t] = (short)f2bf(o[t]);
        }
        __builtin_nontemporal_store(ov, (bf16x8*)(outb + (size_t)i * HID + c0));
#pragma unroll
        for (int t = 0; t < 8; ++t) psum[wave * 2 + sub][c0 + t] = o[t];
    }
    __syncthreads();
    int c = threadIdx.x; // 512 == HID
    float s = 0.f, q = 0.f;
#pragma unroll
    for (int w = 0; w < 16; ++w) {
        float v = psum[w][c];
        s += v; q += v * v;
    }
    int bin = blockIdx.x & (NBINS - 1);
    atomicAdd(&ps[bin * HID + c], s);
    atomicAdd(&pq[bin * HID + c], q);
}

// ---------------- BN prep: fold bins (wave per channel) + zero bins --------
__global__ void bn_prep_kernel(float* __restrict__ ps, float* __restrict__ pq,
                               const float* __restrict__ gamma, const float* __restrict__ beta,
                               float* __restrict__ sc, float* __restrict__ sh, int n) {
    int wave = threadIdx.x >> 6, lane = threadIdx.x & 63;
    int c = blockIdx.x * 8 + wave;
    float s = ps[lane * HID + c] + ps[(lane + 64) * HID + c];
    float q = pq[lane * HID + c] + pq[(lane + 64) * HID + c];
    ps[lane * HID + c] = 0.f; ps[(lane + 64) * HID + c] = 0.f;
    pq[lane * HID + c] = 0.f; pq[(lane + 64) * HID + c] = 0.f;
#pragma unroll
    for (int off = 32; off > 0; off >>= 1) {
        s += __shfl_xor(s, off);
        q += __shfl_xor(q, off);
    }
    if (lane == 0) {
        float inv_n = 1.f / (float)n;
        float mu = s * inv_n;
        float var = q * inv_n - mu * mu;
        float g = rsqrtf(var + 1e-5f) * gamma[c];
        sc[c] = g;
        sh[c] = beta[c] - mu * g;
    }
}

// ---------------- pooling: wave per graph, no atomics ----------------------
__launch_bounds__(256)
__global__ void pool_bn_kernel(const __hip_bfloat16* __restrict__ xb,
                               const int* __restrict__ goff,
                               const float* __restrict__ sc, const float* __restrict__ sh,
                               float* __restrict__ pooled) {
    const int wave = threadIdx.x >> 6, lane = threadIdx.x & 63;
    const int g = blockIdx.x * 4 + wave;
    if (g >= N_GRAPHS) return;
    const int beg = goff[g], end = goff[g + 1];
    const int c0 = lane << 3;
    const float4* scp = reinterpret_cast<const float4*>(sc + c0);
    const float4* shp = reinterpret_cast<const float4*>(sh + c0);
    float4 s0 = scp[0], s1 = scp[1], h0 = shp[0], h1 = shp[1];
    float scv[8] = {s0.x, s0.y, s0.z, s0.w, s1.x, s1.y, s1.z, s1.w};
    float shv[8] = {h0.x, h0.y, h0.z, h0.w, h1.x, h1.y, h1.z, h1.w};
    float acc[8] = {};
    for (int i = beg; i < end; ++i) {
        bf16x8 v = *reinterpret_cast<const bf16x8*>(xb + (size_t)i * HID + c0);
#pragma unroll
        for (int t = 0; t < 8; ++t) {
            float val = fmaf(bf2f((unsigned short)v[t]), scv[t], shv[t]);
            acc[t] += val > 0.f ? val : 0.f;
        }
    }
    int cnt = end - beg;
    float inv = 1.f / (float)(cnt > 0 ? cnt : 1);
    float4 o0 = make_float4(acc[0] * inv, acc[1] * inv, acc[2] * inv, acc[3] * inv);
    float4 o1 = make_float4(acc[4] * inv, acc[5] * inv, acc[6] * inv, acc[7] * inv);
    float4* op = reinterpret_cast<float4*>(pooled + (size_t)g * HID + c0);
    op[0] = o0; op[1] = o1;
}

__global__ void mlp1_kernel(const float* __restrict__ pooled,
                            const float* __restrict__ w1, const float* __restrict__ b1,
                            float* __restrict__ h1) {
    __shared__ float row[HID];
    int g = blockIdx.x;
    int tid = threadIdx.x; // 256
    row[tid] = pooled[(size_t)g * HID + tid];
    row[tid + 256] = pooled[(size_t)g * HID + tid + 256];
    __syncthreads();
    float acc = 0.f;
    for (int c = 0; c < HID; ++c) acc += row[c] * w1[c * 256 + tid];
    float v = acc + b1[tid];
    h1[g * 256 + tid] = v > 0.f ? v : 0.f;
}

__global__ void mlp2_kernel(const float* __restrict__ h1, const float* __restrict__ w2,
                            const float* __restrict__ b2, float* __restrict__ out) {
    __shared__ float row[256];
    int g = blockIdx.x;
    int tid = threadIdx.x; // 64
    for (int j = tid; j < 256; j += 64) row[j] = h1[g * 256 + j];
    __syncthreads();
    if (tid < TARGETS) {
        float acc = 0.f;
        for (int j = 0; j < 256; ++j) acc += row[j] * w2[j * TARGETS + tid];
        out[g * TARGETS + tid] = acc + b2[tid];
    }
}

// ---------------------------------------------------------------------------
extern "C" void kernel_launch(void* const* d_in, const int* in_sizes, int n_in,
                              void* d_out, int out_size, void* d_ws, size_t ws_size,
                              hipStream_t stream) {
    const float* atom   = (const float*)d_in[0];
    const int*   ei     = (const int*)d_in[2];   // [2, N_EDGES]
    const int*   batch  = (const int*)d_in[3];
    const float* atom_w = (const float*)d_in[4];
    const float* atom_b = (const float*)d_in[5];
    const float* gat_w  = (const float*)d_in[6];
    const float* att_s  = (const float*)d_in[7];
    const float* att_d  = (const float*)d_in[8];
    const float* gat_b  = (const float*)d_in[9];
    const float* bn_g   = (const float*)d_in[10];
    const float* bn_b   = (const float*)d_in[11];
    const float* w1     = (const float*)d_in[12];
    const float* b1     = (const float*)d_in[13];
    const float* w2     = (const float*)d_in[14];
    const float* b2     = (const float*)d_in[15];
    float* out = (float*)d_out;

    const int ETOT = N_EDGES + N_NODES;

    char* ws = (char*)d_ws;
    size_t off = 0;
    auto alloc = [&](size_t bytes) {
        void* p = ws + off;
        off += (bytes + 255) & ~(size_t)255;
        return p;
    };
    __hip_bfloat16* xn  = (__hip_bfloat16*)alloc((size_t)N_NODES * HID * 2); // 51.2 MB (atom out)
    __hip_bfloat16* xb  = (__hip_bfloat16*)alloc((size_t)N_NODES * HID * 2); // 51.2 MB (agg out, pre-BN)
    __hip_bfloat16* hb  = (__hip_bfloat16*)alloc((size_t)N_NODES * HID * 2); // 51.2 MB
    __hip_bfloat16* Wt  = (__hip_bfloat16*)alloc((size_t)LAYERS * HID * HID * 2); // 3.1 MB
    __hip_bfloat16* Wt0 = (__hip_bfloat16*)alloc((size_t)HID * 128 * 2);          // 131 KB
    float* as_    = (float*)alloc((size_t)N_NODES * HEADS * 4);
    float* ad_    = (float*)alloc((size_t)N_NODES * HEADS * 4);
    // --- contiguous zero-init region: counts, gcounts, part_s, part_q ---
    size_t zbase = off;
    int* counts   = (int*)alloc(N_NODES * 4);
    int* gcounts  = (int*)alloc(N_GRAPHS * 4);
    float* part_s = (float*)alloc((size_t)NBINS * HID * 4);     // 256 KB
    float* part_q = (float*)alloc((size_t)NBINS * HID * 4);     // 256 KB
    size_t zlen = off - zbase;
    int* offsets  = (int*)alloc((N_NODES + 1) * 4);
    int* wp       = (int*)alloc(N_NODES * 4);
    int* csrc     = (int*)alloc(ETOT * 4);
    int* bsums    = (int*)alloc(64 * 4);
    int* goff     = (int*)alloc((N_GRAPHS + 1) * 4);
    float* bn_sc  = (float*)alloc(HID * 4);
    float* bn_sh  = (float*)alloc(HID * 4);
    float* pooled = (float*)alloc((size_t)N_GRAPHS * HID * 4);
    float* h1     = (float*)alloc((size_t)N_GRAPHS * 256 * 4);

    // ---- single setup memset ----
    hipMemsetAsync(ws + zbase, 0, zlen, stream);

    // ---- edge CSR + graph counting in one pass ----
    count_kernel<<<(ETOT + 255) / 256, 256, 0, stream>>>(ei, batch, counts, gcounts);
    int nb = (N_NODES + 1023) / 1024;
    scan1_kernel<<<nb, 1024, 0, stream>>>(counts, offsets, bsums, N_NODES);
    scan2_kernel<<<1, 64, 0, stream>>>(bsums, nb);
    scan3_kernel<<<nb, 1024, 0, stream>>>(counts, offsets, bsums, wp, N_NODES);
    scatter_kernel<<<(ETOT + 255) / 256, 256, 0, stream>>>(ei, wp, csrc);

    // ---- graph offsets from sorted batch (scan, n=2000) ----
    int nbg = (N_GRAPHS + 1023) / 1024;
    scan1_kernel<<<nbg, 1024, 0, stream>>>(gcounts, goff, bsums, N_GRAPHS);
    scan2_kernel<<<1, 64, 0, stream>>>(bsums, nbg);
    scan3_kernel<<<nbg, 1024, 0, stream>>>(gcounts, goff, bsums, wp, N_GRAPHS);

    // ---- weights: transpose + bf16 convert ----
    wtrans_kernel<<<dim3(HID / 32, HID / 32, LAYERS), dim3(32, 8), 0, stream>>>(gat_w, Wt);
    atomwt_kernel<<<(HID * 128 + 255) / 256, 256, 0, stream>>>(atom_w, Wt0);

    // ---- atom projection -> xn (bf16) via MFMA (K padded to 128) ----
    gemm_atom_kernel<<<dim3((N_NODES + 127) / 128, HID / 128), 256, 0, stream>>>(
        atom, Wt0, atom_b, xn, N_NODES);

    // ---- 6 GAT layers ----
    dim3 ggrid((N_NODES + 127) / 128, HID / 256);
    for (int l = 0; l < LAYERS; ++l) {
        if (l == 0)
            gemm_mfma_kernel<0><<<ggrid, 512, 0, stream>>>(
                xn, Wt, hb, nullptr, nullptr,
                att_s, att_d, as_, ad_, N_NODES);
        else
            gemm_mfma_kernel<1><<<ggrid, 512, 0, stream>>>(
                xb, Wt + (size_t)l * HID * HID, hb, bn_sc, bn_sh,
                att_s + l * HID, att_d + l * HID, as_, ad_, N_NODES);
        agg_kernel<<<N_NODES / 16, 512, 0, stream>>>(hb, as_, ad_, offsets, csrc,
                                                     gat_b + l * HID, xb, part_s, part_q);
        bn_prep_kernel<<<64, 512, 0, stream>>>(part_s, part_q, bn_g + l * HID, bn_b + l * HID,
                                               bn_sc, bn_sh, N_NODES);
    }

    // ---- pool (wave/graph, BN+ReLU fused, atomic-free) + MLP head ----
    pool_bn_kernel<<<(N_GRAPHS + 3) / 4, 256, 0, stream>>>(xb, goff, bn_sc, bn_sh, pooled);
    mlp1_kernel<<<N_GRAPHS, 256, 0, stream>>>(pooled, w1, b1, h1);
    mlp2_kernel<<<N_GRAPHS, 64, 0, stream>>>(h1, w2, b2, out);
}